// Round 15
// baseline (85.114 us; speedup 1.0000x reference)
//
#include <hip/hip_runtime.h>

#define Bn 8
#define Cn 512
#define Hn 8
#define Dn 64
#define Nn 1024
// Q pre-scale: 1/sqrt(64) * log2(e)  -> attention uses exp2 (native v_exp_f32)
#define SCALEQ 0.18033688011112042f

typedef unsigned short u16;
typedef unsigned int u32;
typedef unsigned short u16x8 __attribute__((ext_vector_type(8)));
typedef unsigned short u16x4 __attribute__((ext_vector_type(4)));
typedef unsigned int u32x2 __attribute__((ext_vector_type(2)));
typedef short s16x4 __attribute__((ext_vector_type(4)));
typedef float f32x4 __attribute__((ext_vector_type(4)));
typedef __bf16 bf16x8 __attribute__((ext_vector_type(8)));

__device__ __forceinline__ u16 f2bf(float f){
  unsigned u = __float_as_uint(f);
  u += 0x7fffu + ((u >> 16) & 1u);   // RNE
  return (u16)(u >> 16);
}
__device__ __forceinline__ float bf2f(u16 h){
  return __uint_as_float(((unsigned)h) << 16);
}
__device__ __forceinline__ f32x4 mfma16(u16x8 a, u16x8 b, f32x4 c){
  return __builtin_amdgcn_mfma_f32_16x16x32_bf16(
      __builtin_bit_cast(bf16x8, a), __builtin_bit_cast(bf16x8, b), c, 0, 0, 0);
}
// K=16: A/B layout (lane r,g holds k=4g+j) == 16x16 C/D layout -> P stays in registers
__device__ __forceinline__ f32x4 mfma16k16(u16x4 a, u32x2 b, f32x4 c){
  return __builtin_amdgcn_mfma_f32_16x16x16bf16_1k(
      __builtin_bit_cast(s16x4, a), __builtin_bit_cast(s16x4, b), c, 0, 0, 0);
}
// raw v_exp_f32 (2^x): avoids libm exp2f range-check bloat
__device__ __forceinline__ float fexp2(float x){ return __builtin_amdgcn_exp2f(x); }
// packed f32x2 -> bf16x2 in one instruction
__device__ __forceinline__ u32 cvtpk(float a, float b){
  u32 r;
  asm("v_cvt_pk_bf16_f32 %0, %1, %2" : "=v"(r) : "v"(a), "v"(b));
  return r;
}

// async global->LDS, 16B per lane; dst must be wave-uniform (HW adds lane*16B)
__device__ __forceinline__ void gload16(const u16* src, u16* dst){
  __builtin_amdgcn_global_load_lds(
      (const __attribute__((address_space(1))) unsigned int*)src,
      (__attribute__((address_space(3))) unsigned int*)dst, 16, 0, 0);
}

// T4 counted-vmcnt barrier (gemms): never drain to 0 in the main loop.
#define TILE_SYNC(N) do {                                     \
    asm volatile("s_waitcnt vmcnt(" #N ")" ::: "memory");     \
    __builtin_amdgcn_sched_barrier(0);                        \
    __builtin_amdgcn_s_barrier();                             \
    __builtin_amdgcn_sched_barrier(0);                        \
  } while(0)

// ---------------- pre-pass: transpose (fmap -> fmapT bf16) + weight converts, one launch ----
__global__ __launch_bounds__(256) void k_prep(const float* __restrict__ fmap,
                                              u16* __restrict__ fmapT,
                                              const float* __restrict__ Wqkvl,
                                              const float* __restrict__ Wout,
                                              u16* __restrict__ W1bf, u16* __restrict__ Wobf){
  __shared__ float tile[64][33];
  const int bid = blockIdx.x;
  if (bid < 2048){
    const int n0 = (bid & 31) * 32, c0 = ((bid >> 5) & 7) * 64, b = bid >> 8;
    const int tx = threadIdx.x & 31, ty = threadIdx.x >> 5;   // 32 x 8
    const float* src = fmap + ((size_t)b * Cn + c0) * Nn + n0;
#pragma unroll
    for (int i = 0; i < 8; i++) tile[ty + 8*i][tx] = src[(size_t)(ty + 8*i) * Nn + tx];
    __syncthreads();
    const int nr = threadIdx.x >> 3;          // 0..31 (n within tile)
    const int cj = (threadIdx.x & 7) * 8;     // 0..56 (c within tile)
    u16x8 o;
#pragma unroll
    for (int k = 0; k < 8; k++) o[k] = f2bf(tile[cj + k][nr]);
    *reinterpret_cast<u16x8*>(fmapT + ((size_t)b * Nn + n0 + nr) * Cn + c0 + cj) = o;
  } else {
    const int n1 = Cn*Cn, n2 = Cn*Cn/4;
    int i = (bid - 2048) * 256 + threadIdx.x;
    const float* s; u16* d; int j;
    if (i < n1){ s = Wqkvl; d = W1bf; j = i; }
    else { if (i >= n1 + n2) return; s = Wout; d = Wobf; j = i - n1; }
    float4 f = reinterpret_cast<const float4*>(s)[j];
    u16x4 o;
    o[0] = f2bf(f.x); o[1] = f2bf(f.y); o[2] = f2bf(f.z); o[3] = f2bf(f.w);
    reinterpret_cast<u16x4*>(d)[j] = o;
  }
}

// ---- staging: 128 rows x 32 elem (64B rows), swizzle chunk^=(row&3): 2 gload16 per wave ----
__device__ __forceinline__ void stage128x32(const u16* g, size_t ldg, u16* lbase, int w, int lane){
#pragma unroll
  for (int s = 0; s < 2; s++){
    int row = s*64 + w*16 + (lane>>2);
    gload16(g + (size_t)row*ldg + (((lane&3) ^ (row&3)) * 8), lbase + (s*64 + w*16)*32);
  }
}
// ---- staging: 64 rows x 32 elem (64B rows), swizzle chunk^=(row&3): 1 gload16 per wave ----
__device__ __forceinline__ void stage64x32(const u16* g, size_t ldg, u16* lbase, int w, int lane){
  int row = w*16 + (lane>>2);
  gload16(g + (size_t)row*ldg + (((lane&3) ^ (row&3)) * 8), lbase + (w*16)*32);
}

// ---- NT GEMM 128x128 block tile, BK=32, triple-buffered LDS, counted vmcnt, K = Cn ----
__device__ __forceinline__ void gemm_nt_128(const u16* __restrict__ Ap, int lda,
                                            const u16* __restrict__ Bp, int ldb,
                                            u16* sA, u16* sB,  // [3][128*32] each
                                            f32x4 (&acc)[4][4]){
  const int tid = threadIdx.x;
  const int w = tid >> 6, lane = tid & 63, r = lane & 15, g = lane >> 4;
  const int wi = w >> 1, wj = w & 1;
  stage128x32(Ap,      lda, sA,        w, lane);
  stage128x32(Bp,      ldb, sB,        w, lane);
  stage128x32(Ap + 32, lda, sA + 4096, w, lane);
  stage128x32(Bp + 32, ldb, sB + 4096, w, lane);
  int cur = 0;
  for (int ks = 0; ks < 16; ks++){
    if (ks < 15) TILE_SYNC(4);
    else         TILE_SYNC(0);
    if (ks + 2 < 16){
      int nxt = cur + 2; if (nxt >= 3) nxt -= 3;
      stage128x32(Ap + (ks+2)*32, lda, sA + nxt*4096, w, lane);
      stage128x32(Bp + (ks+2)*32, ldb, sB + nxt*4096, w, lane);
    }
    const u16* Al = sA + cur*4096;
    const u16* Bl = sB + cur*4096;
    u16x8 af[4], bf[4];
#pragma unroll
    for (int t = 0; t < 4; t++){
      int ar = wi*64 + t*16 + r;
      af[t] = *reinterpret_cast<const u16x8*>(&Al[ar*32 + ((g ^ (ar&3)) * 8)]);
      int br = wj*64 + t*16 + r;
      bf[t] = *reinterpret_cast<const u16x8*>(&Bl[br*32 + ((g ^ (br&3)) * 8)]);
    }
#pragma unroll
    for (int i = 0; i < 4; i++)
#pragma unroll
      for (int j = 0; j < 4; j++)
        acc[i][j] = mfma16(af[i], bf[j], acc[i][j]);
    cur = (cur == 2) ? 0 : cur + 1;
  }
}

// ---------------- GEMM1: qkvL = Wqkvl @ fmap  (per batch) ----------------
// Q/L -> [b][n][C] bf16; K -> Kp fragment-major; V -> Vp fragment-major (see k_attn).
__global__ __launch_bounds__(256) void k_gemm1(const u16* __restrict__ fmapT, // [B][N][C]
                                               const u16* __restrict__ W1,    // [2048][C]
                                               u16* __restrict__ Qb, u16* __restrict__ Kp,
                                               u16* __restrict__ Vp, u16* __restrict__ Lb){
  __shared__ u16 sA[3*128*32], sB[3*128*32];   // 48 KB
  const int lin = blockIdx.x;
  const int wid = (lin & 7) * 128 + (lin >> 3);
  const int ob = wid & 15, nb = (wid >> 4) & 7, b = wid >> 7;
  const int w = threadIdx.x >> 6, wi = w >> 1, wj = w & 1;
  const int lane = threadIdx.x & 63, r = lane & 15, g = lane >> 4;
  const int seg = ob >> 2;             // 0=Q 1=K 2=V 3=L

  f32x4 acc[4][4];
  const f32x4 z = {0.f, 0.f, 0.f, 0.f};
#pragma unroll
  for (int i = 0; i < 4; i++)
#pragma unroll
    for (int j = 0; j < 4; j++) acc[i][j] = z;

  const u16* fbase = fmapT + (size_t)b * Nn * Cn;
  // orientation A for ALL segs: D[n][o], n = i (A=fmapT rows), o = j (B=W rows)
  gemm_nt_128(fbase + (size_t)(nb*128) * Cn, Cn, W1 + (size_t)(ob*128) * Cn, Cn, sA, sB, acc);

  if (seg == 0 || seg == 3){
    u16* dst = (seg == 0) ? Qb : Lb;
    const float sc = (seg == 0) ? SCALEQ : 1.0f;
#pragma unroll
    for (int it = 0; it < 4; it++)
#pragma unroll
      for (int jt = 0; jt < 4; jt++)
#pragma unroll
        for (int rr = 0; rr < 4; rr++){
          int n = nb*128 + wi*64 + it*16 + 4*g + rr;
          int o = ob*128 + wj*64 + jt*16 + r;
          dst[((size_t)b * Nn + n) * Cn + (o & 511)] = f2bf(acc[it][jt][rr] * sc);
        }
  } else if (seg == 1){
    // Kp[bh][tile16 = n>>4][chunk = d>>3][key = n&15][d&7]
#pragma unroll
    for (int it = 0; it < 4; it++)
#pragma unroll
      for (int jt = 0; jt < 4; jt++)
#pragma unroll
        for (int rr = 0; rr < 4; rr++){
          int n = nb*128 + wi*64 + it*16 + 4*g + rr;
          int o = ob*128 + wj*64 + jt*16 + r;
          int oo = o - 512, hh = oo >> 6, d = oo & 63;
          size_t off = ((size_t)(b*Hn + hh)*64 + (n>>4))*1024 + (d>>3)*128 + (n&15)*8 + (d&7);
          Kp[off] = f2bf(acc[it][jt][rr]);
        }
  } else {
    // Vp[bh][tile64 = n>>6][s=(n>>4)&3][dt=d>>4][g=(n>>2)&3][key-r=d&15][j=n&3]
    // pack u16x4 over rr (= n&3, stride-1 in Vp) -> 8B stores, 128B contiguous per 16 lanes
#pragma unroll
    for (int it = 0; it < 4; it++)
#pragma unroll
      for (int jt = 0; jt < 4; jt++){
        int n0 = nb*128 + wi*64 + it*16 + 4*g;   // rr=0; n0&3 == 0
        int o = ob*128 + wj*64 + jt*16 + r;
        int oo = o - 1024, hh = oo >> 6, d = oo & 63;
        u16x4 pk;
#pragma unroll
        for (int rr = 0; rr < 4; rr++) pk[rr] = f2bf(acc[it][jt][rr]);
        size_t off = ((size_t)(b*Hn + hh)*16 + (n0>>6))*4096
                   + ((n0>>4)&3)*1024 + (d>>4)*256 + ((n0>>2)&3)*64 + (d&15)*4;
        *reinterpret_cast<u16x4*>(Vp + off) = pk;
      }
  }
}

// ---------------- attention: NO LDS / NO barriers — fragment-major K/V from L2 --------------
// Per 64-key tile: 8 dwordx4 K-loads + 16 dwordx2 V-loads, each a contiguous wave burst.
__global__ __launch_bounds__(256, 2) void k_attn(const u16* __restrict__ Qb,  // [B][N][C] (pre-scaled)
                                                 const u16* __restrict__ Kp,  // frag-major
                                                 const u16* __restrict__ Vp,  // frag-major
                                                 const u16* __restrict__ Lb,  // [B][N][C]
                                                 u16* __restrict__ tok){      // [B][N][C]
  // XCD-bijective swizzle: the 8 q-blocks of one (b,h) share one XCD's L2
  const int bid = blockIdx.x;
  const int w0 = (bid & 7) * 64 + (bid >> 3);
  const int qblk = w0 & 7, h = (w0 >> 3) & 7, b = w0 >> 6;
  const int w = threadIdx.x >> 6, lane = threadIdx.x & 63;
  const int r = lane & 15, g = lane >> 4;
  const int qA = qblk * 128 + w * 16;          // q-tile A
  const int qB = qA + 64;                      // q-tile B

  const u16* qrowA = Qb + ((size_t)b * Nn + qA + r) * Cn + h * Dn + 8 * g;
  const u16* qrowB = Qb + ((size_t)b * Nn + qB + r) * Cn + h * Dn + 8 * g;
  u16x8 qA0 = *reinterpret_cast<const u16x8*>(qrowA);
  u16x8 qA1 = *reinterpret_cast<const u16x8*>(qrowA + 32);
  u16x8 qB0 = *reinterpret_cast<const u16x8*>(qrowB);
  u16x8 qB1 = *reinterpret_cast<const u16x8*>(qrowB + 32);

  const u16* kbase = Kp + (size_t)(b*Hn + h) * 65536 + lane * 8;
  const u16* vbase = Vp + (size_t)(b*Hn + h) * 65536 + lane * 4;

  f32x4 accA[4], accB[4];
  const f32x4 z = {0.f, 0.f, 0.f, 0.f};
#pragma unroll
  for (int dt = 0; dt < 4; dt++){ accA[dt] = z; accB[dt] = z; }
  f32x4 accSA = z, accSB = z;

  for (int tile = 0; tile < 16; tile++){
    const u16* kt = kbase + tile * 4096;
    const u16* vt = vbase + tile * 4096;
    // K frags: lane(r,g) k0 = K[key=16t+r][d=8g..8g+7], k1 = d+32  (coalesced lane*16B)
    u16x8 k0[4], k1[4];
#pragma unroll
    for (int tt = 0; tt < 4; tt++){
      k0[tt] = *reinterpret_cast<const u16x8*>(kt + tt*1024);
      k1[tt] = *reinterpret_cast<const u16x8*>(kt + tt*1024 + 512);
    }
    // V frags: lane(r,g) vf[s][dt] = V[d=dt*16+r][key=16s+4g..+3]  (coalesced lane*8B)
    u16x4 vf[16];
#pragma unroll
    for (int s = 0; s < 4; s++)
#pragma unroll
      for (int dt = 0; dt < 4; dt++)
        vf[s*4+dt] = *reinterpret_cast<const u16x4*>(vt + s*1024 + dt*256);

    // QK^T (swapped): s[t][rr] = S[key = 16t+4g+rr][query r]
    f32x4 sA[4], sB[4];
#pragma unroll
    for (int tt = 0; tt < 4; tt++){
      sA[tt] = mfma16(k0[tt], qA0, z); sA[tt] = mfma16(k1[tt], qA1, sA[tt]);
      sB[tt] = mfma16(k0[tt], qB0, z); sB[tt] = mfma16(k1[tt], qB1, sB[tt]);
    }
    // P = 2^s: raw v_exp_f32 + packed bf16 convert
    u32x2 pA[4], pB[4];
#pragma unroll
    for (int t = 0; t < 4; t++){
      pA[t][0] = cvtpk(fexp2(sA[t][0]), fexp2(sA[t][1]));
      pA[t][1] = cvtpk(fexp2(sA[t][2]), fexp2(sA[t][3]));
      pB[t][0] = cvtpk(fexp2(sB[t][0]), fexp2(sB[t][1]));
      pB[t][1] = cvtpk(fexp2(sB[t][2]), fexp2(sB[t][3]));
    }
    // lsum via ones-MFMA
    const u16x4 ones4 = {0x3F80u, 0x3F80u, 0x3F80u, 0x3F80u};
    const u32x2 onesw = {0x3F803F80u, 0x3F803F80u};
#pragma unroll
    for (int t = 0; t < 4; t++){
      accSA = mfma16k16(ones4, pA[t], accSA);
      accSB = mfma16k16(ones4, pB[t], accSB);
    }
    (void)onesw;
    // PV (swapped): accO[dt] lane holds O[d = dt*16+4g+rr][query r]
#pragma unroll
    for (int s = 0; s < 4; s++)
#pragma unroll
      for (int dt = 0; dt < 4; dt++){
        accA[dt] = mfma16k16(vf[s*4+dt], pA[s], accA[dt]);
        accB[dt] = mfma16k16(vf[s*4+dt], pB[s], accB[dt]);
      }
  }

  // epilogue: lsum already reduced by ones-MFMA; +L, write token-major bf16
  float linvA = 1.0f / accSA[0];
  float linvB = 1.0f / accSB[0];
#pragma unroll
  for (int half = 0; half < 2; half++){
    const int n = (half ? qB : qA) + r;
    const float linv = half ? linvB : linvA;
    const f32x4* acc = half ? accB : accA;
    const u16* lrow = Lb + ((size_t)b * Nn + n) * Cn + h * Dn;
    u16* trow = tok + ((size_t)b * Nn + n) * Cn + h * Dn;
#pragma unroll
    for (int dt = 0; dt < 4; dt++){
      u16x4 lv = *reinterpret_cast<const u16x4*>(lrow + dt*16 + 4*g);
      u16x4 ov;
#pragma unroll
      for (int rr = 0; rr < 4; rr++)
        ov[rr] = f2bf(acc[dt][rr] * linv + bf2f(lv[rr]));
      *reinterpret_cast<u16x4*>(trow + dt*16 + 4*g) = ov;
    }
  }
}

// ---------------- GEMM2: out = Wout @ tok + bout  -> f32 [B][C][N] ----------------
__global__ __launch_bounds__(256) void k_gemm2(const u16* __restrict__ tok, // [B][N][C]
                                               const u16* __restrict__ Wo,  // [C][C]
                                               const float* __restrict__ bout,
                                               float* __restrict__ out){
  __shared__ u16 sA[3*64*32], sB[3*128*32];   // 36 KB
  const int lin = blockIdx.x;
  const int wid = (lin & 7) * 64 + (lin >> 3);   // XCD x owns batch x
  const int ob = wid & 7, nb = (wid >> 3) & 7, b = wid >> 6;
  const int w = threadIdx.x >> 6, wi = w >> 1, wj = w & 1;
  const int lane = threadIdx.x & 63, r = lane & 15, g = lane >> 4;

  f32x4 acc[2][4];
  const f32x4 z = {0.f, 0.f, 0.f, 0.f};
#pragma unroll
  for (int i = 0; i < 2; i++)
#pragma unroll
    for (int j = 0; j < 4; j++) acc[i][j] = z;

  const u16* Ap = Wo + (size_t)(ob*64) * Cn;
  const u16* Bp = tok + (size_t)b * Nn * Cn + (size_t)(nb*128) * Cn;

  stage64x32 (Ap,      Cn, sA,        w, lane);
  stage128x32(Bp,      Cn, sB,        w, lane);
  stage64x32 (Ap + 32, Cn, sA + 2048, w, lane);
  stage128x32(Bp + 32, Cn, sB + 4096, w, lane);
  int cur = 0;
  for (int ks = 0; ks < 16; ks++){
    if (ks < 15) TILE_SYNC(3);
    else         TILE_SYNC(0);
    if (ks + 2 < 16){
      int nxt = cur + 2; if (nxt >= 3) nxt -= 3;
      stage64x32 (Ap + (ks+2)*32, Cn, sA + nxt*2048, w, lane);
      stage128x32(Bp + (ks+2)*32, Cn, sB + nxt*4096, w, lane);
    }
    const u16* Al = sA + cur*2048;
    const u16* Bl = sB + cur*4096;
    u16x8 af[2], bf[4];
#pragma unroll
    for (int t = 0; t < 2; t++){
      int ar = wi*32 + t*16 + r;
      af[t] = *reinterpret_cast<const u16x8*>(&Al[ar*32 + ((g ^ (ar&3)) * 8)]);
    }
#pragma unroll
    for (int t = 0; t < 4; t++){
      int br = wj*64 + t*16 + r;
      bf[t] = *reinterpret_cast<const u16x8*>(&Bl[br*32 + ((g ^ (br&3)) * 8)]);
    }
#pragma unroll
    for (int i = 0; i < 2; i++)
#pragma unroll
      for (int j = 0; j < 4; j++)
        acc[i][j] = mfma16(af[i], bf[j], acc[i][j]);
    cur = (cur == 2) ? 0 : cur + 1;
  }

#pragma unroll
  for (int it = 0; it < 2; it++)
#pragma unroll
    for (int jt = 0; jt < 4; jt++)
#pragma unroll
      for (int rr = 0; rr < 4; rr++){
        int o = ob*64 + wi*32 + it*16 + 4*g + rr;
        int n = nb*128 + wj*64 + jt*16 + r;
        out[((size_t)b * Cn + o) * Nn + n] = acc[it][jt][rr] + bout[o];
      }
}

extern "C" void kernel_launch(void* const* d_in, const int* in_sizes, int n_in,
                              void* d_out, int out_size, void* d_ws, size_t ws_size,
                              hipStream_t stream){
  const float* fmap  = (const float*)d_in[0];
  const float* Wqkvl = (const float*)d_in[1];
  const float* Wout  = (const float*)d_in[2];
  const float* bout  = (const float*)d_in[3];
  float* out = (float*)d_out;

  char* ws = (char*)d_ws;
  size_t off = 0;
  auto alloc = [&](size_t bytes) -> void* {
    void* p = ws + off;
    off += (bytes + 255) & ~(size_t)255;
    return p;
  };
  u16* W1bf  = (u16*)alloc((size_t)4*Cn*Cn*2);
  u16* Wobf  = (u16*)alloc((size_t)Cn*Cn*2);
  u16* fmapT = (u16*)alloc((size_t)Bn*Nn*Cn*2);
  u16* Qb    = (u16*)alloc((size_t)Bn*Nn*Cn*2);
  u16* Kp    = (u16*)alloc((size_t)Bn*Hn*Nn*Dn*2);   // fragment-major K
  u16* Lb    = (u16*)alloc((size_t)Bn*Nn*Cn*2);
  u16* Vp    = (u16*)alloc((size_t)Bn*Hn*Dn*Nn*2);   // fragment-major V
  u16* tok   = fmapT;   // fmapT dead after gemm1; reuse for attention output

  hipLaunchKernelGGL(k_prep, dim3(2048 + 1280), dim3(256), 0, stream,
                     fmap, fmapT, Wqkvl, Wout, W1bf, Wobf);
  hipLaunchKernelGGL(k_gemm1, dim3(1024), dim3(256), 0, stream, fmapT, W1bf, Qb, Kp, Vp, Lb);
  hipLaunchKernelGGL(k_attn, dim3(512), dim3(256), 0, stream, Qb, Kp, Vp, Lb, tok);
  hipLaunchKernelGGL(k_gemm2, dim3(512), dim3(256), 0, stream, tok, Wobf, bout, out);
}

// Round 16
// 82.323 us; speedup vs baseline: 1.0339x; 1.0339x over previous
//
#include <hip/hip_runtime.h>

#define Bn 8
#define Cn 512
#define Hn 8
#define Dn 64
#define Nn 1024
// Q pre-scale: 1/sqrt(64) * log2(e)  -> attention uses exp2 (native v_exp_f32)
#define SCALEQ 0.18033688011112042f

typedef unsigned short u16;
typedef unsigned int u32;
typedef unsigned short u16x8 __attribute__((ext_vector_type(8)));
typedef unsigned short u16x4 __attribute__((ext_vector_type(4)));
typedef unsigned int u32x2 __attribute__((ext_vector_type(2)));
typedef short s16x4 __attribute__((ext_vector_type(4)));
typedef float f32x4 __attribute__((ext_vector_type(4)));
typedef __bf16 bf16x8 __attribute__((ext_vector_type(8)));

__device__ __forceinline__ u16 f2bf(float f){
  unsigned u = __float_as_uint(f);
  u += 0x7fffu + ((u >> 16) & 1u);   // RNE
  return (u16)(u >> 16);
}
__device__ __forceinline__ float bf2f(u16 h){
  return __uint_as_float(((unsigned)h) << 16);
}
__device__ __forceinline__ f32x4 mfma16(u16x8 a, u16x8 b, f32x4 c){
  return __builtin_amdgcn_mfma_f32_16x16x32_bf16(
      __builtin_bit_cast(bf16x8, a), __builtin_bit_cast(bf16x8, b), c, 0, 0, 0);
}
// K=16: A/B layout (lane r,g holds k=4g+j) == 16x16 C/D layout -> P stays in registers
__device__ __forceinline__ f32x4 mfma16k16(u16x4 a, u32x2 b, f32x4 c){
  return __builtin_amdgcn_mfma_f32_16x16x16bf16_1k(
      __builtin_bit_cast(s16x4, a), __builtin_bit_cast(s16x4, b), c, 0, 0, 0);
}
// raw v_exp_f32 (2^x): avoids libm exp2f range-check bloat
__device__ __forceinline__ float fexp2(float x){ return __builtin_amdgcn_exp2f(x); }
// packed f32x2 -> bf16x2 in one instruction
__device__ __forceinline__ u32 cvtpk(float a, float b){
  u32 r;
  asm("v_cvt_pk_bf16_f32 %0, %1, %2" : "=v"(r) : "v"(a), "v"(b));
  return r;
}

// async global->LDS, 16B per lane; dst must be wave-uniform (HW adds lane*16B)
__device__ __forceinline__ void gload16(const u16* src, u16* dst){
  __builtin_amdgcn_global_load_lds(
      (const __attribute__((address_space(1))) unsigned int*)src,
      (__attribute__((address_space(3))) unsigned int*)dst, 16, 0, 0);
}

// T4 counted-vmcnt barrier: never drain to 0 in the main loop.
#define TILE_SYNC(N) do {                                     \
    asm volatile("s_waitcnt vmcnt(" #N ")" ::: "memory");     \
    __builtin_amdgcn_sched_barrier(0);                        \
    __builtin_amdgcn_s_barrier();                             \
    __builtin_amdgcn_sched_barrier(0);                        \
  } while(0)

// ---------------- pre-pass: transpose (fmap -> fmapT bf16) + weight converts, one launch ----
__global__ __launch_bounds__(256) void k_prep(const float* __restrict__ fmap,
                                              u16* __restrict__ fmapT,
                                              const float* __restrict__ Wqkvl,
                                              const float* __restrict__ Wout,
                                              u16* __restrict__ W1bf, u16* __restrict__ Wobf){
  __shared__ float tile[64][33];
  const int bid = blockIdx.x;
  if (bid < 2048){
    // transpose: 32n x 64c tile;  nb = bid&31, cb = (bid>>5)&7, b = bid>>8
    const int n0 = (bid & 31) * 32, c0 = ((bid >> 5) & 7) * 64, b = bid >> 8;
    const int tx = threadIdx.x & 31, ty = threadIdx.x >> 5;   // 32 x 8
    const float* src = fmap + ((size_t)b * Cn + c0) * Nn + n0;
#pragma unroll
    for (int i = 0; i < 8; i++) tile[ty + 8*i][tx] = src[(size_t)(ty + 8*i) * Nn + tx];
    __syncthreads();
    const int nr = threadIdx.x >> 3;          // 0..31 (n within tile)
    const int cj = (threadIdx.x & 7) * 8;     // 0..56 (c within tile)
    u16x8 o;
#pragma unroll
    for (int k = 0; k < 8; k++) o[k] = f2bf(tile[cj + k][nr]);
    *reinterpret_cast<u16x8*>(fmapT + ((size_t)b * Nn + n0 + nr) * Cn + c0 + cj) = o;
  } else {
    // weight convert: n1 = Cn*Cn float4s (Wqkvl), n2 = Cn*Cn/4 float4s (Wout)
    const int n1 = Cn*Cn, n2 = Cn*Cn/4;
    int i = (bid - 2048) * 256 + threadIdx.x;
    const float* s; u16* d; int j;
    if (i < n1){ s = Wqkvl; d = W1bf; j = i; }
    else { if (i >= n1 + n2) return; s = Wout; d = Wobf; j = i - n1; }
    float4 f = reinterpret_cast<const float4*>(s)[j];
    u16x4 o;
    o[0] = f2bf(f.x); o[1] = f2bf(f.y); o[2] = f2bf(f.z); o[3] = f2bf(f.w);
    reinterpret_cast<u16x4*>(d)[j] = o;
  }
}

// ---- staging (4-wave): 64 rows x 64 elem (128B rows, 8x16B chunks), chunk ^= (row&7) ----
__device__ __forceinline__ void stage64(const u16* g, size_t ldg, u16* lbase, int w, int lane){
#pragma unroll
  for (int s = 0; s < 2; s++){
    int row = s*32 + w*8 + (lane>>3);
    gload16(g + (size_t)row*ldg + (((lane&7) ^ (row&7)) * 8), lbase + (s*32 + w*8)*64);
  }
}
// ---- staging: 128 rows x 32 elem (64B rows), swizzle chunk^=(row&3): 2 gload16 per wave ----
__device__ __forceinline__ void stage128x32(const u16* g, size_t ldg, u16* lbase, int w, int lane){
#pragma unroll
  for (int s = 0; s < 2; s++){
    int row = s*64 + w*16 + (lane>>2);
    gload16(g + (size_t)row*ldg + (((lane&3) ^ (row&3)) * 8), lbase + (s*64 + w*16)*32);
  }
}
// ---- staging: 64 rows x 32 elem (64B rows), swizzle chunk^=(row&3): 1 gload16 per wave ----
__device__ __forceinline__ void stage64x32(const u16* g, size_t ldg, u16* lbase, int w, int lane){
  int row = w*16 + (lane>>2);
  gload16(g + (size_t)row*ldg + (((lane&3) ^ (row&3)) * 8), lbase + (w*16)*32);
}

// ---- NT GEMM 128x128 block tile, BK=32, triple-buffered LDS, counted vmcnt, K = Cn ----
// (setprio-free: m190 — setprio hurts lockstep GEMM)
__device__ __forceinline__ void gemm_nt_128(const u16* __restrict__ Ap, int lda,
                                            const u16* __restrict__ Bp, int ldb,
                                            u16* sA, u16* sB,  // [3][128*32] each
                                            f32x4 (&acc)[4][4]){
  const int tid = threadIdx.x;
  const int w = tid >> 6, lane = tid & 63, r = lane & 15, g = lane >> 4;
  const int wi = w >> 1, wj = w & 1;
  stage128x32(Ap,      lda, sA,        w, lane);
  stage128x32(Bp,      ldb, sB,        w, lane);
  stage128x32(Ap + 32, lda, sA + 4096, w, lane);
  stage128x32(Bp + 32, ldb, sB + 4096, w, lane);
  int cur = 0;
  for (int ks = 0; ks < 16; ks++){
    if (ks < 15) TILE_SYNC(4);
    else         TILE_SYNC(0);
    if (ks + 2 < 16){
      int nxt = cur + 2; if (nxt >= 3) nxt -= 3;
      stage128x32(Ap + (ks+2)*32, lda, sA + nxt*4096, w, lane);
      stage128x32(Bp + (ks+2)*32, ldb, sB + nxt*4096, w, lane);
    }
    const u16* Al = sA + cur*4096;
    const u16* Bl = sB + cur*4096;
    u16x8 af[4], bf[4];
#pragma unroll
    for (int t = 0; t < 4; t++){
      int ar = wi*64 + t*16 + r;
      af[t] = *reinterpret_cast<const u16x8*>(&Al[ar*32 + ((g ^ (ar&3)) * 8)]);
      int br = wj*64 + t*16 + r;
      bf[t] = *reinterpret_cast<const u16x8*>(&Bl[br*32 + ((g ^ (br&3)) * 8)]);
    }
#pragma unroll
    for (int i = 0; i < 4; i++)
#pragma unroll
      for (int j = 0; j < 4; j++)
        acc[i][j] = mfma16(af[i], bf[j], acc[i][j]);
    cur = (cur == 2) ? 0 : cur + 1;
  }
}

// ---------------- GEMM1: qkvL = Wqkvl @ fmap  (per batch) ----------------
__global__ __launch_bounds__(256) void k_gemm1(const u16* __restrict__ fmapT, // [B][N][C]
                                               const u16* __restrict__ W1,    // [2048][C]
                                               u16* __restrict__ Qb, u16* __restrict__ Kb,
                                               u16* __restrict__ Vt, u16* __restrict__ Lb){
  __shared__ u16 sA[3*128*32], sB[3*128*32];   // 48 KB
  const int lin = blockIdx.x;
  const int wid = (lin & 7) * 128 + (lin >> 3);
  const int ob = wid & 15, nb = (wid >> 4) & 7, b = wid >> 7;
  const int w = threadIdx.x >> 6, wi = w >> 1, wj = w & 1;
  const int lane = threadIdx.x & 63, r = lane & 15, g = lane >> 4;
  const int seg = ob >> 2;             // 0=Q 1=K 2=V 3=L

  f32x4 acc[4][4];
  const f32x4 z = {0.f, 0.f, 0.f, 0.f};
#pragma unroll
  for (int i = 0; i < 4; i++)
#pragma unroll
    for (int j = 0; j < 4; j++) acc[i][j] = z;

  const u16* fbase = fmapT + (size_t)b * Nn * Cn;

  if (seg != 2){
    gemm_nt_128(fbase + (size_t)(nb*128) * Cn, Cn, W1 + (size_t)(ob*128) * Cn, Cn, sA, sB, acc);
    u16* dst = (seg == 0) ? Qb : (seg == 1 ? Kb : Lb);
    const float sc = (seg == 0) ? SCALEQ : 1.0f;
#pragma unroll
    for (int it = 0; it < 4; it++)
#pragma unroll
      for (int jt = 0; jt < 4; jt++)
#pragma unroll
        for (int rr = 0; rr < 4; rr++){
          int n = nb*128 + wi*64 + it*16 + 4*g + rr;
          int o = ob*128 + wj*64 + jt*16 + r;
          dst[((size_t)b * Nn + n) * Cn + (o & 511)] = f2bf(acc[it][jt][rr] * sc);
        }
  } else {
    gemm_nt_128(W1 + (size_t)(ob*128) * Cn, Cn, fbase + (size_t)(nb*128) * Cn, Cn, sA, sB, acc);
#pragma unroll
    for (int it = 0; it < 4; it++)
#pragma unroll
      for (int jt = 0; jt < 4; jt++)
#pragma unroll
        for (int rr = 0; rr < 4; rr++){
          int o = ob*128 + wi*64 + it*16 + 4*g + rr;
          int oo = o - 1024;
          int h = oo >> 6, d = oo & 63;
          int n = nb*128 + wj*64 + jt*16 + r;
          Vt[(((size_t)b * Hn + h) * Dn + d) * Nn + n] = f2bf(acc[it][jt][rr]);
        }
  }
}

// ---------------- attention: diet softmax, triple-buffer counted-vmcnt, LDS-shared K/V ------
__global__ __launch_bounds__(256, 4) void k_attn(const u16* __restrict__ Qb,  // [B][N][C] (pre-scaled)
                                                 const u16* __restrict__ Kb,  // [B][N][C]
                                                 const u16* __restrict__ Vt,  // [B][H][D][N]
                                                 const u16* __restrict__ Lb,  // [B][N][C]
                                                 u16* __restrict__ tok){      // [B][N][C]
  __shared__ u16 Kl[3*64*64], Vl[3*64*64];   // 48 KB, triple-buffered
  const int bid = blockIdx.x;
  const int w0 = (bid & 7) * 64 + (bid >> 3);
  const int qblk = w0 & 7, h = (w0 >> 3) & 7, b = w0 >> 6;
  const int w = threadIdx.x >> 6, lane = threadIdx.x & 63;
  const int r = lane & 15, g = lane >> 4;
  const int qA = qblk * 128 + w * 16;          // q-tile A
  const int qB = qA + 64;                      // q-tile B

  const u16* qrowA = Qb + ((size_t)b * Nn + qA + r) * Cn + h * Dn + 8 * g;
  const u16* qrowB = Qb + ((size_t)b * Nn + qB + r) * Cn + h * Dn + 8 * g;
  u16x8 qA0 = *reinterpret_cast<const u16x8*>(qrowA);
  u16x8 qA1 = *reinterpret_cast<const u16x8*>(qrowA + 32);
  u16x8 qB0 = *reinterpret_cast<const u16x8*>(qrowB);
  u16x8 qB1 = *reinterpret_cast<const u16x8*>(qrowB + 32);

  const u16* kbase = Kb + (size_t)b * Nn * Cn + h * Dn;
  const u16* vbase = Vt + ((size_t)b * Hn + h) * Dn * Nn;

  // per-lane LDS read bases, computed once
  const int koff0 = r*64 + ((g     ^ (r&7)) * 8);
  const int koff1 = r*64 + (((4+g) ^ (r&7)) * 8);
  int voff[4];
#pragma unroll
  for (int s = 0; s < 4; s++)
    voff[s] = r*64 + (((2*s + (g>>1)) ^ (r&7)) * 8) + (g&1)*4;

  f32x4 accA[4], accB[4];
  const f32x4 z = {0.f, 0.f, 0.f, 0.f};
#pragma unroll
  for (int dt = 0; dt < 4; dt++){ accA[dt] = z; accB[dt] = z; }
  f32x4 accSA = z, accSB = z;

  // prologue: stage tiles 0,1 -> 8 loads/wave outstanding
  stage64(kbase,         Cn, Kl,        w, lane);
  stage64(vbase,         Nn, Vl,        w, lane);
  stage64(kbase + 64*Cn, Cn, Kl + 4096, w, lane);
  stage64(vbase + 64,    Nn, Vl + 4096, w, lane);

  int cur = 0;
  for (int tile = 0; tile < 16; tile++){
    if (tile < 15) TILE_SYNC(4);
    else           TILE_SYNC(0);
    if (tile + 2 < 16){
      int nxt = cur + 2; if (nxt >= 3) nxt -= 3;
      stage64(kbase + (size_t)(tile+2)*64*Cn, Cn, Kl + nxt*4096, w, lane);
      stage64(vbase + (tile+2)*64,            Nn, Vl + nxt*4096, w, lane);
    }
    const u16* kp0 = Kl + cur*4096 + koff0;
    const u16* kp1 = Kl + cur*4096 + koff1;
    const u16* vp0 = Vl + cur*4096 + voff[0];
    const u16* vp1 = Vl + cur*4096 + voff[1];
    const u16* vp2 = Vl + cur*4096 + voff[2];
    const u16* vp3 = Vl + cur*4096 + voff[3];

    // QK^T (swapped): s[t][rr] = S[key = 16t+4g+rr][query r]
    f32x4 sA[4], sB[4];
    __builtin_amdgcn_s_setprio(1);
#pragma unroll
    for (int t = 0; t < 4; t++){
      u16x8 k0 = *reinterpret_cast<const u16x8*>(kp0 + t*1024);
      u16x8 k1 = *reinterpret_cast<const u16x8*>(kp1 + t*1024);
      sA[t] = mfma16(k0, qA0, z); sA[t] = mfma16(k1, qA1, sA[t]);
      sB[t] = mfma16(k0, qB0, z); sB[t] = mfma16(k1, qB1, sB[t]);
    }
    __builtin_amdgcn_s_setprio(0);
    // P = 2^s: raw v_exp_f32 + packed bf16 convert
    u32x2 pA[4], pB[4];
#pragma unroll
    for (int t = 0; t < 4; t++){
      pA[t][0] = cvtpk(fexp2(sA[t][0]), fexp2(sA[t][1]));
      pA[t][1] = cvtpk(fexp2(sA[t][2]), fexp2(sA[t][3]));
      pB[t][0] = cvtpk(fexp2(sB[t][0]), fexp2(sB[t][1]));
      pB[t][1] = cvtpk(fexp2(sB[t][2]), fexp2(sB[t][3]));
    }
    // lsum via ones-MFMA + PV (swapped)
    const u32x2 ones = {0x3F803F80u, 0x3F803F80u};
    __builtin_amdgcn_s_setprio(1);
#pragma unroll
    for (int t = 0; t < 4; t++){
      accSA = mfma16k16(ones[0] == 0 ? u16x4{} : *(const u16x4*)&ones, pA[t], accSA);
      accSB = mfma16k16(*(const u16x4*)&ones, pB[t], accSB);
    }
#pragma unroll
    for (int s = 0; s < 4; s++){
      const u16* vp = (s == 0) ? vp0 : (s == 1) ? vp1 : (s == 2) ? vp2 : vp3;
#pragma unroll
      for (int dt = 0; dt < 4; dt++){
        u16x4 vf = *reinterpret_cast<const u16x4*>(vp + dt*1024);
        accA[dt] = mfma16k16(vf, pA[s], accA[dt]);
        accB[dt] = mfma16k16(vf, pB[s], accB[dt]);
      }
    }
    __builtin_amdgcn_s_setprio(0);
    cur = (cur == 2) ? 0 : cur + 1;
  }

  // epilogue: lsum already reduced by ones-MFMA; +L, write token-major bf16
  float linvA = 1.0f / accSA[0];
  float linvB = 1.0f / accSB[0];
#pragma unroll
  for (int half = 0; half < 2; half++){
    const int n = (half ? qB : qA) + r;
    const float linv = half ? linvB : linvA;
    const f32x4* acc = half ? accB : accA;
    const u16* lrow = Lb + ((size_t)b * Nn + n) * Cn + h * Dn;
    u16* trow = tok + ((size_t)b * Nn + n) * Cn + h * Dn;
#pragma unroll
    for (int dt = 0; dt < 4; dt++){
      u16x4 lv = *reinterpret_cast<const u16x4*>(lrow + dt*16 + 4*g);
      u16x4 ov;
#pragma unroll
      for (int rr = 0; rr < 4; rr++)
        ov[rr] = f2bf(acc[dt][rr] * linv + bf2f(lv[rr]));
      *reinterpret_cast<u16x4*>(trow + dt*16 + 4*g) = ov;
    }
  }
}

// ---------------- GEMM2: out = Wout @ tok + bout  -> f32 [B][C][N] ----------------
// 64o x 128n tiles, 512 blocks, triple-buffered counted-vmcnt
__global__ __launch_bounds__(256) void k_gemm2(const u16* __restrict__ tok, // [B][N][C]
                                               const u16* __restrict__ Wo,  // [C][C]
                                               const float* __restrict__ bout,
                                               float* __restrict__ out){
  __shared__ u16 sA[3*64*32], sB[3*128*32];   // 36 KB
  const int lin = blockIdx.x;
  const int wid = (lin & 7) * 64 + (lin >> 3);   // XCD x owns batch x
  const int ob = wid & 7, nb = (wid >> 3) & 7, b = wid >> 6;
  const int w = threadIdx.x >> 6, wi = w >> 1, wj = w & 1;
  const int lane = threadIdx.x & 63, r = lane & 15, g = lane >> 4;

  f32x4 acc[2][4];
  const f32x4 z = {0.f, 0.f, 0.f, 0.f};
#pragma unroll
  for (int i = 0; i < 2; i++)
#pragma unroll
    for (int j = 0; j < 4; j++) acc[i][j] = z;

  const u16* Ap = Wo + (size_t)(ob*64) * Cn;
  const u16* Bp = tok + (size_t)b * Nn * Cn + (size_t)(nb*128) * Cn;

  stage64x32 (Ap,      Cn, sA,        w, lane);
  stage128x32(Bp,      Cn, sB,        w, lane);
  stage64x32 (Ap + 32, Cn, sA + 2048, w, lane);
  stage128x32(Bp + 32, Cn, sB + 4096, w, lane);
  int cur = 0;
  for (int ks = 0; ks < 16; ks++){
    if (ks < 15) TILE_SYNC(3);
    else         TILE_SYNC(0);
    if (ks + 2 < 16){
      int nxt = cur + 2; if (nxt >= 3) nxt -= 3;
      stage64x32 (Ap + (ks+2)*32, Cn, sA + nxt*2048, w, lane);
      stage128x32(Bp + (ks+2)*32, Cn, sB + nxt*4096, w, lane);
    }
    const u16* Al = sA + cur*2048;
    const u16* Bl = sB + cur*4096;
    u16x8 af[2], bf[4];
#pragma unroll
    for (int t = 0; t < 2; t++){
      int ar = wi*32 + t*16 + r;
      af[t] = *reinterpret_cast<const u16x8*>(&Al[ar*32 + ((g ^ (ar&3)) * 8)]);
    }
#pragma unroll
    for (int t = 0; t < 4; t++){
      int br = wj*64 + t*16 + r;
      bf[t] = *reinterpret_cast<const u16x8*>(&Bl[br*32 + ((g ^ (br&3)) * 8)]);
    }
#pragma unroll
    for (int i = 0; i < 2; i++)
#pragma unroll
      for (int j = 0; j < 4; j++)
        acc[i][j] = mfma16(af[i], bf[j], acc[i][j]);
    cur = (cur == 2) ? 0 : cur + 1;
  }

#pragma unroll
  for (int it = 0; it < 2; it++)
#pragma unroll
    for (int jt = 0; jt < 4; jt++)
#pragma unroll
      for (int rr = 0; rr < 4; rr++){
        int o = ob*64 + wi*32 + it*16 + 4*g + rr;
        int n = nb*128 + wj*64 + jt*16 + r;
        out[((size_t)b * Cn + o) * Nn + n] = acc[it][jt][rr] + bout[o];
      }
}

extern "C" void kernel_launch(void* const* d_in, const int* in_sizes, int n_in,
                              void* d_out, int out_size, void* d_ws, size_t ws_size,
                              hipStream_t stream){
  const float* fmap  = (const float*)d_in[0];
  const float* Wqkvl = (const float*)d_in[1];
  const float* Wout  = (const float*)d_in[2];
  const float* bout  = (const float*)d_in[3];
  float* out = (float*)d_out;

  char* ws = (char*)d_ws;
  size_t off = 0;
  auto alloc = [&](size_t bytes) -> void* {
    void* p = ws + off;
    off += (bytes + 255) & ~(size_t)255;
    return p;
  };
  u16* W1bf  = (u16*)alloc((size_t)4*Cn*Cn*2);
  u16* Wobf  = (u16*)alloc((size_t)Cn*Cn*2);
  u16* fmapT = (u16*)alloc((size_t)Bn*Nn*Cn*2);
  u16* Qb    = (u16*)alloc((size_t)Bn*Nn*Cn*2);
  u16* Kb    = (u16*)alloc((size_t)Bn*Nn*Cn*2);
  u16* Lb    = (u16*)alloc((size_t)Bn*Nn*Cn*2);
  u16* Vt    = (u16*)alloc((size_t)Bn*Hn*Dn*Nn*2);
  u16* tok   = fmapT;   // fmapT dead after gemm1; reuse for attention output

  // prep grid: 2048 transpose blocks + (Cn*Cn + Cn*Cn/4)/256 = 1280 convert blocks
  hipLaunchKernelGGL(k_prep, dim3(2048 + 1280), dim3(256), 0, stream,
                     fmap, fmapT, Wqkvl, Wout, W1bf, Wobf);
  hipLaunchKernelGGL(k_gemm1, dim3(1024), dim3(256), 0, stream, fmapT, W1bf, Qb, Kb, Vt, Lb);
  hipLaunchKernelGGL(k_attn, dim3(512), dim3(256), 0, stream, Qb, Kb, Vt, Lb, tok);
  hipLaunchKernelGGL(k_gemm2, dim3(512), dim3(256), 0, stream, tok, Wobf, bout, out);
}

// Round 17
// 81.412 us; speedup vs baseline: 1.0455x; 1.0112x over previous
//
#include <hip/hip_runtime.h>

#define Bn 8
#define Cn 512
#define Hn 8
#define Dn 64
#define Nn 1024
// Q pre-scale: 1/sqrt(64) * log2(e)  -> attention uses exp2 (native v_exp_f32)
#define SCALEQ 0.18033688011112042f

typedef unsigned short u16;
typedef unsigned int u32;
typedef unsigned short u16x8 __attribute__((ext_vector_type(8)));
typedef unsigned short u16x4 __attribute__((ext_vector_type(4)));
typedef unsigned int u32x2 __attribute__((ext_vector_type(2)));
typedef short s16x4 __attribute__((ext_vector_type(4)));
typedef float f32x4 __attribute__((ext_vector_type(4)));
typedef __bf16 bf16x8 __attribute__((ext_vector_type(8)));

__device__ __forceinline__ u16 f2bf(float f){
  unsigned u = __float_as_uint(f);
  u += 0x7fffu + ((u >> 16) & 1u);   // RNE
  return (u16)(u >> 16);
}
__device__ __forceinline__ float bf2f(u16 h){
  return __uint_as_float(((unsigned)h) << 16);
}
__device__ __forceinline__ f32x4 mfma16(u16x8 a, u16x8 b, f32x4 c){
  return __builtin_amdgcn_mfma_f32_16x16x32_bf16(
      __builtin_bit_cast(bf16x8, a), __builtin_bit_cast(bf16x8, b), c, 0, 0, 0);
}
// K=16: A/B layout (lane r,g holds k=4g+j) == 16x16 C/D layout -> P stays in registers
__device__ __forceinline__ f32x4 mfma16k16(u16x4 a, u32x2 b, f32x4 c){
  return __builtin_amdgcn_mfma_f32_16x16x16bf16_1k(
      __builtin_bit_cast(s16x4, a), __builtin_bit_cast(s16x4, b), c, 0, 0, 0);
}
// raw v_exp_f32 (2^x): avoids libm exp2f range-check bloat
__device__ __forceinline__ float fexp2(float x){ return __builtin_amdgcn_exp2f(x); }
// packed f32x2 -> bf16x2 in one instruction
__device__ __forceinline__ u32 cvtpk(float a, float b){
  u32 r;
  asm("v_cvt_pk_bf16_f32 %0, %1, %2" : "=v"(r) : "v"(a), "v"(b));
  return r;
}

// async global->LDS, 16B per lane; dst must be wave-uniform (HW adds lane*16B)
__device__ __forceinline__ void gload16(const u16* src, u16* dst){
  __builtin_amdgcn_global_load_lds(
      (const __attribute__((address_space(1))) unsigned int*)src,
      (__attribute__((address_space(3))) unsigned int*)dst, 16, 0, 0);
}

// T4 counted-vmcnt barrier (attn + gemm2): never drain to 0 in the main loop.
#define TILE_SYNC(N) do {                                     \
    asm volatile("s_waitcnt vmcnt(" #N ")" ::: "memory");     \
    __builtin_amdgcn_sched_barrier(0);                        \
    __builtin_amdgcn_s_barrier();                             \
    __builtin_amdgcn_sched_barrier(0);                        \
  } while(0)

// ---------------- pre-pass: transpose (fmap -> fmapT bf16) + weight converts, one launch ----
__global__ __launch_bounds__(256) void k_prep(const float* __restrict__ fmap,
                                              u16* __restrict__ fmapT,
                                              const float* __restrict__ Wqkvl,
                                              const float* __restrict__ Wout,
                                              u16* __restrict__ W1bf, u16* __restrict__ Wobf){
  __shared__ float tile[64][33];
  const int bid = blockIdx.x;
  if (bid < 2048){
    // transpose: 32n x 64c tile;  nb = bid&31, cb = (bid>>5)&7, b = bid>>8
    const int n0 = (bid & 31) * 32, c0 = ((bid >> 5) & 7) * 64, b = bid >> 8;
    const int tx = threadIdx.x & 31, ty = threadIdx.x >> 5;   // 32 x 8
    const float* src = fmap + ((size_t)b * Cn + c0) * Nn + n0;
#pragma unroll
    for (int i = 0; i < 8; i++) tile[ty + 8*i][tx] = src[(size_t)(ty + 8*i) * Nn + tx];
    __syncthreads();
    const int nr = threadIdx.x >> 3;          // 0..31 (n within tile)
    const int cj = (threadIdx.x & 7) * 8;     // 0..56 (c within tile)
    u16x8 o;
#pragma unroll
    for (int k = 0; k < 8; k++) o[k] = f2bf(tile[cj + k][nr]);
    *reinterpret_cast<u16x8*>(fmapT + ((size_t)b * Nn + n0 + nr) * Cn + c0 + cj) = o;
  } else {
    // weight convert: n1 = Cn*Cn float4s (Wqkvl), n2 = Cn*Cn/4 float4s (Wout)
    const int n1 = Cn*Cn, n2 = Cn*Cn/4;
    int i = (bid - 2048) * 256 + threadIdx.x;
    const float* s; u16* d; int j;
    if (i < n1){ s = Wqkvl; d = W1bf; j = i; }
    else { if (i >= n1 + n2) return; s = Wout; d = Wobf; j = i - n1; }
    float4 f = reinterpret_cast<const float4*>(s)[j];
    u16x4 o;
    o[0] = f2bf(f.x); o[1] = f2bf(f.y); o[2] = f2bf(f.z); o[3] = f2bf(f.w);
    reinterpret_cast<u16x4*>(d)[j] = o;
  }
}

// ---- staging (4-wave): 64 rows x 64 elem (128B rows, 8x16B chunks), chunk ^= (row&7) ----
__device__ __forceinline__ void stage64(const u16* g, size_t ldg, u16* lbase, int w, int lane){
#pragma unroll
  for (int s = 0; s < 2; s++){
    int row = s*32 + w*8 + (lane>>3);
    gload16(g + (size_t)row*ldg + (((lane&7) ^ (row&7)) * 8), lbase + (s*32 + w*8)*64);
  }
}
// ---- staging: 128 rows x 32 elem (64B rows), swizzle chunk^=(row&3): 2 gload16 per wave ----
__device__ __forceinline__ void stage128x32(const u16* g, size_t ldg, u16* lbase, int w, int lane){
#pragma unroll
  for (int s = 0; s < 2; s++){
    int row = s*64 + w*16 + (lane>>2);
    gload16(g + (size_t)row*ldg + (((lane&3) ^ (row&3)) * 8), lbase + (s*64 + w*16)*32);
  }
}
// ---- staging: 64 rows x 32 elem (64B rows), swizzle chunk^=(row&3): 1 gload16 per wave ----
__device__ __forceinline__ void stage64x32(const u16* g, size_t ldg, u16* lbase, int w, int lane){
  int row = w*16 + (lane>>2);
  gload16(g + (size_t)row*ldg + (((lane&3) ^ (row&3)) * 8), lbase + (w*16)*32);
}

// ---- NT GEMM 128x128 block tile, BK=32, DOUBLE-buffered drain-0 (m97 structure), K = Cn ----
// 32 KB LDS -> 4 blocks/CU resident (grid = 4/CU exactly); dbuf ≈ counted-3buf in throughput
// (m97 912 TF vs m131-141 839-890) but wins back the residency slot.
__device__ __forceinline__ void gemm_nt_128(const u16* __restrict__ Ap, int lda,
                                            const u16* __restrict__ Bp, int ldb,
                                            u16* sA, u16* sB,  // [2][128*32] each
                                            f32x4 (&acc)[4][4]){
  const int tid = threadIdx.x;
  const int w = tid >> 6, lane = tid & 63, r = lane & 15, g = lane >> 4;
  const int wi = w >> 1, wj = w & 1;
  stage128x32(Ap, lda, sA, w, lane);
  stage128x32(Bp, ldb, sB, w, lane);
  for (int ks = 0; ks < 16; ks++){
    __syncthreads();                       // buf[ks&1] staged; prior reads done
    const int cur = ks & 1;
    if (ks + 1 < 16){
      stage128x32(Ap + (ks+1)*32, lda, sA + (cur^1)*4096, w, lane);
      stage128x32(Bp + (ks+1)*32, ldb, sB + (cur^1)*4096, w, lane);
    }
    const u16* Al = sA + cur*4096;
    const u16* Bl = sB + cur*4096;
    u16x8 af[4], bf[4];
#pragma unroll
    for (int t = 0; t < 4; t++){
      int ar = wi*64 + t*16 + r;
      af[t] = *reinterpret_cast<const u16x8*>(&Al[ar*32 + ((g ^ (ar&3)) * 8)]);
      int br = wj*64 + t*16 + r;
      bf[t] = *reinterpret_cast<const u16x8*>(&Bl[br*32 + ((g ^ (br&3)) * 8)]);
    }
#pragma unroll
    for (int i = 0; i < 4; i++)
#pragma unroll
      for (int j = 0; j < 4; j++)
        acc[i][j] = mfma16(af[i], bf[j], acc[i][j]);
  }
}

// ---------------- GEMM1: qkvL = Wqkvl @ fmap  (per batch) ----------------
__global__ __launch_bounds__(256) void k_gemm1(const u16* __restrict__ fmapT, // [B][N][C]
                                               const u16* __restrict__ W1,    // [2048][C]
                                               u16* __restrict__ Qb, u16* __restrict__ Kb,
                                               u16* __restrict__ Vt, u16* __restrict__ Lb){
  __shared__ u16 sA[2*128*32], sB[2*128*32];   // 32 KB -> 4 blocks/CU
  const int lin = blockIdx.x;
  const int wid = (lin & 7) * 128 + (lin >> 3);
  const int ob = wid & 15, nb = (wid >> 4) & 7, b = wid >> 7;
  const int w = threadIdx.x >> 6, wi = w >> 1, wj = w & 1;
  const int lane = threadIdx.x & 63, r = lane & 15, g = lane >> 4;
  const int seg = ob >> 2;             // 0=Q 1=K 2=V 3=L

  f32x4 acc[4][4];
  const f32x4 z = {0.f, 0.f, 0.f, 0.f};
#pragma unroll
  for (int i = 0; i < 4; i++)
#pragma unroll
    for (int j = 0; j < 4; j++) acc[i][j] = z;

  const u16* fbase = fmapT + (size_t)b * Nn * Cn;

  if (seg != 2){
    gemm_nt_128(fbase + (size_t)(nb*128) * Cn, Cn, W1 + (size_t)(ob*128) * Cn, Cn, sA, sB, acc);
    u16* dst = (seg == 0) ? Qb : (seg == 1 ? Kb : Lb);
    const float sc = (seg == 0) ? SCALEQ : 1.0f;
#pragma unroll
    for (int it = 0; it < 4; it++)
#pragma unroll
      for (int jt = 0; jt < 4; jt++)
#pragma unroll
        for (int rr = 0; rr < 4; rr++){
          int n = nb*128 + wi*64 + it*16 + 4*g + rr;
          int o = ob*128 + wj*64 + jt*16 + r;
          dst[((size_t)b * Nn + n) * Cn + (o & 511)] = f2bf(acc[it][jt][rr] * sc);
        }
  } else {
    gemm_nt_128(W1 + (size_t)(ob*128) * Cn, Cn, fbase + (size_t)(nb*128) * Cn, Cn, sA, sB, acc);
#pragma unroll
    for (int it = 0; it < 4; it++)
#pragma unroll
      for (int jt = 0; jt < 4; jt++)
#pragma unroll
        for (int rr = 0; rr < 4; rr++){
          int o = ob*128 + wi*64 + it*16 + 4*g + rr;
          int oo = o - 1024;
          int h = oo >> 6, d = oo & 63;
          int n = nb*128 + wj*64 + jt*16 + r;
          Vt[(((size_t)b * Hn + h) * Dn + d) * Nn + n] = f2bf(acc[it][jt][rr]);
        }
  }
}

// ---------------- attention: diet softmax, triple-buffer counted-vmcnt, LDS-shared K/V ------
__global__ __launch_bounds__(256, 4) void k_attn(const u16* __restrict__ Qb,  // [B][N][C] (pre-scaled)
                                                 const u16* __restrict__ Kb,  // [B][N][C]
                                                 const u16* __restrict__ Vt,  // [B][H][D][N]
                                                 const u16* __restrict__ Lb,  // [B][N][C]
                                                 u16* __restrict__ tok){      // [B][N][C]
  __shared__ u16 Kl[3*64*64], Vl[3*64*64];   // 48 KB, triple-buffered
  const int bid = blockIdx.x;
  const int w0 = (bid & 7) * 64 + (bid >> 3);
  const int qblk = w0 & 7, h = (w0 >> 3) & 7, b = w0 >> 6;
  const int w = threadIdx.x >> 6, lane = threadIdx.x & 63;
  const int r = lane & 15, g = lane >> 4;
  const int qA = qblk * 128 + w * 16;          // q-tile A
  const int qB = qA + 64;                      // q-tile B

  const u16* qrowA = Qb + ((size_t)b * Nn + qA + r) * Cn + h * Dn + 8 * g;
  const u16* qrowB = Qb + ((size_t)b * Nn + qB + r) * Cn + h * Dn + 8 * g;
  u16x8 qA0 = *reinterpret_cast<const u16x8*>(qrowA);
  u16x8 qA1 = *reinterpret_cast<const u16x8*>(qrowA + 32);
  u16x8 qB0 = *reinterpret_cast<const u16x8*>(qrowB);
  u16x8 qB1 = *reinterpret_cast<const u16x8*>(qrowB + 32);

  const u16* kbase = Kb + (size_t)b * Nn * Cn + h * Dn;
  const u16* vbase = Vt + ((size_t)b * Hn + h) * Dn * Nn;

  // per-lane LDS read bases, computed once
  const int koff0 = r*64 + ((g     ^ (r&7)) * 8);
  const int koff1 = r*64 + (((4+g) ^ (r&7)) * 8);
  int voff[4];
#pragma unroll
  for (int s = 0; s < 4; s++)
    voff[s] = r*64 + (((2*s + (g>>1)) ^ (r&7)) * 8) + (g&1)*4;

  f32x4 accA[4], accB[4];
  const f32x4 z = {0.f, 0.f, 0.f, 0.f};
#pragma unroll
  for (int dt = 0; dt < 4; dt++){ accA[dt] = z; accB[dt] = z; }
  f32x4 accSA = z, accSB = z;

  // prologue: stage tiles 0,1 -> 8 loads/wave outstanding
  stage64(kbase,         Cn, Kl,        w, lane);
  stage64(vbase,         Nn, Vl,        w, lane);
  stage64(kbase + 64*Cn, Cn, Kl + 4096, w, lane);
  stage64(vbase + 64,    Nn, Vl + 4096, w, lane);

  int cur = 0;
  for (int tile = 0; tile < 16; tile++){
    if (tile < 15) TILE_SYNC(4);
    else           TILE_SYNC(0);
    if (tile + 2 < 16){
      int nxt = cur + 2; if (nxt >= 3) nxt -= 3;
      stage64(kbase + (size_t)(tile+2)*64*Cn, Cn, Kl + nxt*4096, w, lane);
      stage64(vbase + (tile+2)*64,            Nn, Vl + nxt*4096, w, lane);
    }
    const u16* kp0 = Kl + cur*4096 + koff0;
    const u16* kp1 = Kl + cur*4096 + koff1;
    const u16* vp0 = Vl + cur*4096 + voff[0];
    const u16* vp1 = Vl + cur*4096 + voff[1];
    const u16* vp2 = Vl + cur*4096 + voff[2];
    const u16* vp3 = Vl + cur*4096 + voff[3];

    // QK^T (swapped): s[t][rr] = S[key = 16t+4g+rr][query r]
    f32x4 sA[4], sB[4];
    __builtin_amdgcn_s_setprio(1);
#pragma unroll
    for (int t = 0; t < 4; t++){
      u16x8 k0 = *reinterpret_cast<const u16x8*>(kp0 + t*1024);
      u16x8 k1 = *reinterpret_cast<const u16x8*>(kp1 + t*1024);
      sA[t] = mfma16(k0, qA0, z); sA[t] = mfma16(k1, qA1, sA[t]);
      sB[t] = mfma16(k0, qB0, z); sB[t] = mfma16(k1, qB1, sB[t]);
    }
    __builtin_amdgcn_s_setprio(0);
    // P = 2^s: raw v_exp_f32 + packed bf16 convert
    u32x2 pA[4], pB[4];
#pragma unroll
    for (int t = 0; t < 4; t++){
      pA[t][0] = cvtpk(fexp2(sA[t][0]), fexp2(sA[t][1]));
      pA[t][1] = cvtpk(fexp2(sA[t][2]), fexp2(sA[t][3]));
      pB[t][0] = cvtpk(fexp2(sB[t][0]), fexp2(sB[t][1]));
      pB[t][1] = cvtpk(fexp2(sB[t][2]), fexp2(sB[t][3]));
    }
    // lsum via ones-MFMA + PV (swapped)
    const u32x2 ones = {0x3F803F80u, 0x3F803F80u};
    __builtin_amdgcn_s_setprio(1);
#pragma unroll
    for (int t = 0; t < 4; t++){
      accSA = mfma16k16(ones[0] == 0 ? u16x4{} : *(const u16x4*)&ones, pA[t], accSA);
      accSB = mfma16k16(*(const u16x4*)&ones, pB[t], accSB);
    }
#pragma unroll
    for (int s = 0; s < 4; s++){
      const u16* vp = (s == 0) ? vp0 : (s == 1) ? vp1 : (s == 2) ? vp2 : vp3;
#pragma unroll
      for (int dt = 0; dt < 4; dt++){
        u16x4 vf = *reinterpret_cast<const u16x4*>(vp + dt*1024);
        accA[dt] = mfma16k16(vf, pA[s], accA[dt]);
        accB[dt] = mfma16k16(vf, pB[s], accB[dt]);
      }
    }
    __builtin_amdgcn_s_setprio(0);
    cur = (cur == 2) ? 0 : cur + 1;
  }

  // epilogue: lsum already reduced by ones-MFMA; +L, write token-major bf16
  float linvA = 1.0f / accSA[0];
  float linvB = 1.0f / accSB[0];
#pragma unroll
  for (int half = 0; half < 2; half++){
    const int n = (half ? qB : qA) + r;
    const float linv = half ? linvB : linvA;
    const f32x4* acc = half ? accB : accA;
    const u16* lrow = Lb + ((size_t)b * Nn + n) * Cn + h * Dn;
    u16* trow = tok + ((size_t)b * Nn + n) * Cn + h * Dn;
#pragma unroll
    for (int dt = 0; dt < 4; dt++){
      u16x4 lv = *reinterpret_cast<const u16x4*>(lrow + dt*16 + 4*g);
      u16x4 ov;
#pragma unroll
      for (int rr = 0; rr < 4; rr++)
        ov[rr] = f2bf(acc[dt][rr] * linv + bf2f(lv[rr]));
      *reinterpret_cast<u16x4*>(trow + dt*16 + 4*g) = ov;
    }
  }
}

// ---------------- GEMM2: out = Wout @ tok + bout  -> f32 [B][C][N] ----------------
// 64o x 128n tiles, 512 blocks, triple-buffered counted-vmcnt (36 KB -> 4 blocks/CU, fine)
__global__ __launch_bounds__(256) void k_gemm2(const u16* __restrict__ tok, // [B][N][C]
                                               const u16* __restrict__ Wo,  // [C][C]
                                               const float* __restrict__ bout,
                                               float* __restrict__ out){
  __shared__ u16 sA[3*64*32], sB[3*128*32];   // 36 KB
  const int lin = blockIdx.x;
  const int wid = (lin & 7) * 64 + (lin >> 3);   // XCD x owns batch x
  const int ob = wid & 7, nb = (wid >> 3) & 7, b = wid >> 6;
  const int w = threadIdx.x >> 6, wi = w >> 1, wj = w & 1;
  const int lane = threadIdx.x & 63, r = lane & 15, g = lane >> 4;

  f32x4 acc[2][4];
  const f32x4 z = {0.f, 0.f, 0.f, 0.f};
#pragma unroll
  for (int i = 0; i < 2; i++)
#pragma unroll
    for (int j = 0; j < 4; j++) acc[i][j] = z;

  const u16* Ap = Wo + (size_t)(ob*64) * Cn;
  const u16* Bp = tok + (size_t)b * Nn * Cn + (size_t)(nb*128) * Cn;

  stage64x32 (Ap,      Cn, sA,        w, lane);
  stage128x32(Bp,      Cn, sB,        w, lane);
  stage64x32 (Ap + 32, Cn, sA + 2048, w, lane);
  stage128x32(Bp + 32, Cn, sB + 4096, w, lane);
  int cur = 0;
  for (int ks = 0; ks < 16; ks++){
    if (ks < 15) TILE_SYNC(3);
    else         TILE_SYNC(0);
    if (ks + 2 < 16){
      int nxt = cur + 2; if (nxt >= 3) nxt -= 3;
      stage64x32 (Ap + (ks+2)*32, Cn, sA + nxt*2048, w, lane);
      stage128x32(Bp + (ks+2)*32, Cn, sB + nxt*4096, w, lane);
    }
    const u16* Al = sA + cur*2048;
    const u16* Bl = sB + cur*4096;
    u16x8 af[2], bf[4];
#pragma unroll
    for (int t = 0; t < 2; t++){
      int ar = wi*32 + t*16 + r;
      af[t] = *reinterpret_cast<const u16x8*>(&Al[ar*32 + ((g ^ (ar&3)) * 8)]);
    }
#pragma unroll
    for (int t = 0; t < 4; t++){
      int br = wj*64 + t*16 + r;
      bf[t] = *reinterpret_cast<const u16x8*>(&Bl[br*32 + ((g ^ (br&3)) * 8)]);
    }
#pragma unroll
    for (int i = 0; i < 2; i++)
#pragma unroll
      for (int j = 0; j < 4; j++)
        acc[i][j] = mfma16(af[i], bf[j], acc[i][j]);
    cur = (cur == 2) ? 0 : cur + 1;
  }

#pragma unroll
  for (int it = 0; it < 2; it++)
#pragma unroll
    for (int jt = 0; jt < 4; jt++)
#pragma unroll
      for (int rr = 0; rr < 4; rr++){
        int o = ob*64 + wi*32 + it*16 + 4*g + rr;
        int n = nb*128 + wj*64 + jt*16 + r;
        out[((size_t)b * Cn + o) * Nn + n] = acc[it][jt][rr] + bout[o];
      }
}

extern "C" void kernel_launch(void* const* d_in, const int* in_sizes, int n_in,
                              void* d_out, int out_size, void* d_ws, size_t ws_size,
                              hipStream_t stream){
  const float* fmap  = (const float*)d_in[0];
  const float* Wqkvl = (const float*)d_in[1];
  const float* Wout  = (const float*)d_in[2];
  const float* bout  = (const float*)d_in[3];
  float* out = (float*)d_out;

  char* ws = (char*)d_ws;
  size_t off = 0;
  auto alloc = [&](size_t bytes) -> void* {
    void* p = ws + off;
    off += (bytes + 255) & ~(size_t)255;
    return p;
  };
  u16* W1bf  = (u16*)alloc((size_t)4*Cn*Cn*2);
  u16* Wobf  = (u16*)alloc((size_t)Cn*Cn*2);
  u16* fmapT = (u16*)alloc((size_t)Bn*Nn*Cn*2);
  u16* Qb    = (u16*)alloc((size_t)Bn*Nn*Cn*2);
  u16* Kb    = (u16*)alloc((size_t)Bn*Nn*Cn*2);
  u16* Lb    = (u16*)alloc((size_t)Bn*Nn*Cn*2);
  u16* Vt    = (u16*)alloc((size_t)Bn*Hn*Dn*Nn*2);
  u16* tok   = fmapT;   // fmapT dead after gemm1; reuse for attention output

  // prep grid: 2048 transpose blocks + (Cn*Cn + Cn*Cn/4)/256 = 1280 convert blocks
  hipLaunchKernelGGL(k_prep, dim3(2048 + 1280), dim3(256), 0, stream,
                     fmap, fmapT, Wqkvl, Wout, W1bf, Wobf);
  hipLaunchKernelGGL(k_gemm1, dim3(1024), dim3(256), 0, stream, fmapT, W1bf, Qb, Kb, Vt, Lb);
  hipLaunchKernelGGL(k_attn, dim3(512), dim3(256), 0, stream, Qb, Kb, Vt, Lb, tok);
  hipLaunchKernelGGL(k_gemm2, dim3(512), dim3(256), 0, stream, tok, Wobf, bout, out);
}